// Round 1
// baseline (549.060 us; speedup 1.0000x reference)
//
#include <hip/hip_runtime.h>

// Fused Conv3x3(8->64) + bias + GroupNorm(16) + scale + MaxPool4x4 + clamp
// One workgroup per (batch, group): conv streamed through a rolling LDS row
// buffer; GN handled via (sum,sumsq) + affine-commuted maxpool (keep window
// max AND min of raw conv output; pick by sign of per-channel affine slope).

constexpr int CI   = 8;
constexpr int CO   = 64;
constexpr int HIN  = 128;
constexpr int WIN_ = 128;
constexpr int HO_  = 126;
constexpr int WO_  = 126;
constexpr int CPG  = 4;    // channels per group
constexpr int PW   = 31;   // pooled H/W
constexpr float EPS = 1e-5f;

__global__ __launch_bounds__(256, 2)
void fused_conv_gn_pool(const float* __restrict__ x,
                        const float* __restrict__ cw,
                        const float* __restrict__ cb,
                        const float* __restrict__ gnw,
                        const float* __restrict__ gnb,
                        const float* __restrict__ scl,
                        float* __restrict__ out)
{
    __shared__ float xb[6][CI][WIN_];        // rolling input rows   24576 B
    __shared__ float wl[CI][3][3][CPG];      // weights              1152 B
    __shared__ float rmax[4][CPG][PW];       // per-window-row max   1984 B
    __shared__ float rmin[4][CPG][PW];       //                      1984 B
    __shared__ float wmaxs[CPG][PW][PW];     // window max           15376 B
    __shared__ float wmins[CPG][PW][PW];     // window min           15376 B
    __shared__ float redbuf[4][2];
    __shared__ float statbuf[2];

    const int t   = threadIdx.x;
    const int bid = blockIdx.x;
    const int b   = bid >> 4;
    const int g   = bid & 15;
    const int co0 = g * CPG;

    // stage weights: wl[ci][kh][kw][c] (c contiguous -> ds_read_b128 taps)
    for (int i = t; i < CI * 9 * CPG; i += 256) {
        int c    = i & 3;
        int rest = i >> 2;
        int kw   = rest % 3;
        int kh   = (rest / 3) % 3;
        int ci   = rest / 9;
        wl[ci][kh][kw][c] = cw[((co0 + c) * CI + ci) * 9 + kh * 3 + kw];
    }

    float bb[CPG];
    #pragma unroll
    for (int c = 0; c < CPG; ++c) bb[c] = cb[co0 + c];

    const int col  = t & 127;       // output column (0..127, active < 126)
    const int half = t >> 7;        // which pair of rows in the 4-row block
    const float* xbase = x + (size_t)b * CI * HIN * WIN_;

    float s1 = 0.f, s2 = 0.f;

    for (int j = 0; j < 32; ++j) {
        // ---- stage new input rows into rolling buffer (slot = row % 6) ----
        const int r0    = (j == 0) ? 0 : 4 * j + 2;
        const int nload = (j == 0) ? 6 : ((4 * j + 6 <= 128) ? 4 : (128 - r0));
        __syncthreads();
        for (int i = t; i < nload * CI * WIN_; i += 256) {
            int cc = i & 127;
            int ci = (i >> 7) & 7;
            int rr = i >> 10;
            int gr = r0 + rr;
            xb[gr % 6][ci][cc] = xbase[(ci * HIN + gr) * WIN_ + cc];
        }
        __syncthreads();

        // ---- conv: this thread = 2 output rows (orow, orow+1) at `col` ----
        const int orow = 4 * j + 2 * half;
        if (orow < HO_ && col < WO_) {
            float a0[CPG] = {0.f, 0.f, 0.f, 0.f};
            float a1[CPG] = {0.f, 0.f, 0.f, 0.f};
            int sl[4];
            {
                int sb = orow % 6;
                #pragma unroll
                for (int ir = 0; ir < 4; ++ir) {
                    int s = sb + ir;
                    sl[ir] = (s >= 6) ? s - 6 : s;
                }
            }
            for (int ci = 0; ci < CI; ++ci) {
                float xv[4][3];
                #pragma unroll
                for (int ir = 0; ir < 4; ++ir) {
                    xv[ir][0] = xb[sl[ir]][ci][col];
                    xv[ir][1] = xb[sl[ir]][ci][col + 1];
                    xv[ir][2] = xb[sl[ir]][ci][col + 2];
                }
                #pragma unroll
                for (int kh = 0; kh < 3; ++kh)
                #pragma unroll
                for (int kw = 0; kw < 3; ++kw) {
                    #pragma unroll
                    for (int c = 0; c < CPG; ++c) {
                        float w = wl[ci][kh][kw][c];
                        a0[c] = fmaf(w, xv[kh][kw], a0[c]);
                        a1[c] = fmaf(w, xv[kh + 1][kw], a1[c]);
                    }
                }
            }
            #pragma unroll
            for (int c = 0; c < CPG; ++c) {
                a0[c] += bb[c];
                a1[c] += bb[c];
                s1 += a0[c] + a1[c];
                s2 += a0[c] * a0[c] + a1[c] * a1[c];
            }
            // 4-col pool reduce (lanes 4k..4k+3 are cols 4k..4k+3)
            if (j < 31) {
                #pragma unroll
                for (int c = 0; c < CPG; ++c) {
                    float m0 = fmaxf(a0[c], __shfl_xor(a0[c], 1));
                    m0       = fmaxf(m0,   __shfl_xor(m0, 2));
                    float n0 = fminf(a0[c], __shfl_xor(a0[c], 1));
                    n0       = fminf(n0,   __shfl_xor(n0, 2));
                    float m1 = fmaxf(a1[c], __shfl_xor(a1[c], 1));
                    m1       = fmaxf(m1,   __shfl_xor(m1, 2));
                    float n1 = fminf(a1[c], __shfl_xor(a1[c], 1));
                    n1       = fminf(n1,   __shfl_xor(n1, 2));
                    if ((col & 3) == 0 && col < 124) {
                        int pj = col >> 2;
                        rmax[2 * half + 0][c][pj] = m0;
                        rmin[2 * half + 0][c][pj] = n0;
                        rmax[2 * half + 1][c][pj] = m1;
                        rmin[2 * half + 1][c][pj] = n1;
                    }
                }
            }
        }
        __syncthreads();
        // ---- 4-row combine -> window max/min for window-row j ----
        if (j < 31 && t < CPG * PW) {
            int c  = t / PW;
            int pj = t - c * PW;
            float M = fmaxf(fmaxf(rmax[0][c][pj], rmax[1][c][pj]),
                            fmaxf(rmax[2][c][pj], rmax[3][c][pj]));
            float N = fminf(fminf(rmin[0][c][pj], rmin[1][c][pj]),
                            fminf(rmin[2][c][pj], rmin[3][c][pj]));
            wmaxs[c][j][pj] = M;
            wmins[c][j][pj] = N;
        }
    }

    // ---- GroupNorm stats reduction (sum, sumsq over whole group) ----
    #pragma unroll
    for (int off = 1; off < 64; off <<= 1) {
        s1 += __shfl_xor(s1, off);
        s2 += __shfl_xor(s2, off);
    }
    if ((t & 63) == 0) {
        redbuf[t >> 6][0] = s1;
        redbuf[t >> 6][1] = s2;
    }
    __syncthreads();
    if (t == 0) {
        float S1 = 0.f, S2 = 0.f;
        #pragma unroll
        for (int w = 0; w < 4; ++w) { S1 += redbuf[w][0]; S2 += redbuf[w][1]; }
        const float invN = 1.0f / (float)(CPG * HO_ * WO_);
        float mean = S1 * invN;
        float var  = S2 * invN - mean * mean;
        statbuf[0] = mean;
        statbuf[1] = rsqrtf(var + EPS);
    }
    __syncthreads();
    const float mean = statbuf[0];
    const float inv  = statbuf[1];

    // ---- epilogue: affine + pick max/min by slope sign + clamp + store ----
    for (int i = t; i < CPG * PW * PW; i += 256) {
        int c   = i / (PW * PW);
        int rem = i - c * PW * PW;
        int pi  = rem / PW;
        int pj  = rem - pi * PW;
        int co  = co0 + c;
        float A = inv * gnw[co] * scl[co];
        float B = (gnb[co] - mean * inv * gnw[co]) * scl[co];
        float v = (A > 0.f) ? fmaf(A, wmaxs[c][pi][pj], B)
                            : fmaf(A, wmins[c][pi][pj], B);
        v = fminf(fmaxf(v, 0.f), 1.f);
        out[(((size_t)b * CO + co) * PW + pi) * PW + pj] = v;
    }
}

extern "C" void kernel_launch(void* const* d_in, const int* in_sizes, int n_in,
                              void* d_out, int out_size, void* d_ws, size_t ws_size,
                              hipStream_t stream) {
    const float* x   = (const float*)d_in[0];
    const float* cw  = (const float*)d_in[1];
    const float* cb  = (const float*)d_in[2];
    const float* gnw = (const float*)d_in[3];
    const float* gnb = (const float*)d_in[4];
    const float* scl = (const float*)d_in[5];
    float* out = (float*)d_out;

    fused_conv_gn_pool<<<dim3(128 * 16), dim3(256), 0, stream>>>(
        x, cw, cb, gnw, gnb, scl, out);
}